// Round 18
// baseline (72.979 us; speedup 1.0000x reference)
//
#include <hip/hip_runtime.h>
#include <hip/hip_bf16.h>

#define BATCH 8192
#define DMODEL 4096
#define NEXP 64

typedef __attribute__((ext_vector_type(8))) short short8;   // 8 bf16 (4 VGPR)
typedef __attribute__((ext_vector_type(4))) float f32x4;

// direct global->LDS async copy, 16B per lane; LDS dest = wave-uniform base + lane*16
#define GLD16(dst_lds, src_g)                                                  \
    __builtin_amdgcn_global_load_lds(                                          \
        (const __attribute__((address_space(1))) void*)(src_g),                \
        (__attribute__((address_space(3))) void*)(dst_lds), 16, 0, 0)

#define CVT1(V, J, AH, AM, AL) {                                              \
    const float xv_ = (V);                                                    \
    const __hip_bfloat16 h_ = __float2bfloat16(xv_);                          \
    const float r1_ = xv_ - __bfloat162float(h_);                             \
    const __hip_bfloat16 m_ = __float2bfloat16(r1_);                          \
    const float r2_ = r1_ - __bfloat162float(m_);                             \
    const __hip_bfloat16 l_ = __float2bfloat16(r2_);                          \
    AH[J] = (short)__builtin_bit_cast(unsigned short, h_);                    \
    AM[J] = (short)__builtin_bit_cast(unsigned short, m_);                    \
    AL[J] = (short)__builtin_bit_cast(unsigned short, l_); }

#define CVT8(X0, X1, AH, AM, AL)                                              \
    CVT1(X0[0], 0, AH, AM, AL) CVT1(X0[1], 1, AH, AM, AL)                     \
    CVT1(X0[2], 2, AH, AM, AL) CVT1(X0[3], 3, AH, AM, AL)                     \
    CVT1(X1[0], 4, AH, AM, AL) CVT1(X1[1], 5, AH, AM, AL)                     \
    CVT1(X1[2], 6, AH, AM, AL) CVT1(X1[3], 7, AH, AM, AL)

#define MFMA(A, B, C) __builtin_amdgcn_mfma_f32_16x16x32_bf16(A, B, C, 0, 0, 0)

// ============================================================================
// MFMA GEMM, W converted in-kernel (no precomputed planes, no build dispatch):
// 256 threads (4 waves), 64x64 tile, BK=32. A and W fp32 both staged via
// global_load_lds with pre-swizzled source (same index math: row-major [r][4096]).
// Per cf: 2 ds_read_b128 fp32 W -> CVT to h/m/l in regs -> 6 MFMA.
// LDS 32 KB double-buffered -> 4 blocks/CU. Counted vmcnt(4), 2-barrier phase.
// Block 0 zeroes the accumulator region (router runs after kernel boundary).
// Grid = 128 row-groups x S k-splits. part[s][row][e].
// ============================================================================
__global__ __launch_bounds__(256, 4) void gemm_mfma(const float* __restrict__ x,
                                                    const float* __restrict__ W,
                                                    float* __restrict__ part,
                                                    float* __restrict__ zbase,
                                                    int S)
{
    __shared__ float xs[2][2048];            // A tiles: [buf][64 rows * 32 k], 8 KB each
    __shared__ float wlds[2][2048];          // W tiles: [buf][64 e * 32 k] fp32, 8 KB each

    const int t = threadIdx.x;
    const int l = t & 63;
    const int wid = t >> 6;
    const int g = blockIdx.x & 127;          // row group (64 rows)
    const int s = blockIdx.x >> 7;           // k-split
    const int rowbase = g * 64;
    const int kbeg = s * (DMODEL / S);
    const int nsteps = (DMODEL / S) >> 5;    // 32-k steps

    if (blockIdx.x == 0) {                   // zero probsum/counts/done for router
        zbase[t] = 0.f;
        zbase[t + 256] = 0.f;
    }

    // ---- staging sources (pre-swizzled): row r_, stored unit l&7,
    //      logical unit (l&7)^(row&7); row&7 == l>>3 for both A and W.
    const float* pxa[2];
    const float* pwa[2];
#pragma unroll
    for (int r = 0; r < 2; ++r) {
        const int rr = wid * 16 + r * 8 + (l >> 3);
        const int ul = (l & 7) ^ (l >> 3);
        pxa[r] = x + (size_t)(rowbase + rr) * DMODEL + kbeg + ul * 4;
        pwa[r] = W + (size_t)rr * DMODEL + kbeg + ul * 4;
    }

#define STAGE(BUF, IT) {                                                       \
    _Pragma("unroll")                                                          \
    for (int r_ = 0; r_ < 2; ++r_)                                             \
        GLD16(&xs[BUF][wid * 512 + r_ * 256], pxa[r_] + (size_t)(IT) * 32);    \
    _Pragma("unroll")                                                          \
    for (int r_ = 0; r_ < 2; ++r_)                                             \
        GLD16(&wlds[BUF][wid * 512 + r_ * 256], pwa[r_] + (size_t)(IT) * 32); }

    // ---- compute-side addresses (same XOR on read)
    const int lr = l & 15;
    const int lk = l >> 4;
    const int xr = lr & 7;
    const int trw = wid * 16 + lr;
    const int a0 = trw * 32 + (((lk * 2)     ^ xr) * 4);
    const int a1 = trw * 32 + (((lk * 2 + 1) ^ xr) * 4);
    // B frag: e = cf*16 + lr  ->  e&7 == xr; same unit swizzle
    int bofs[4];
#pragma unroll
    for (int cf = 0; cf < 4; ++cf)
        bofs[cf] = (cf * 16 + lr) * 32;
    const int b0o = ((lk * 2)     ^ xr) * 4;
    const int b1o = ((lk * 2 + 1) ^ xr) * 4;

    f32x4 acc[4] = {};

    STAGE(0, 0)

    for (int it = 0; it < nsteps; ++it) {
        const int cur = it & 1;
        if (it + 1 < nsteps) {
            STAGE(cur ^ 1, it + 1)
            asm volatile("s_waitcnt vmcnt(4)" ::: "memory");
        } else {
            asm volatile("s_waitcnt vmcnt(0)" ::: "memory");
        }
        __builtin_amdgcn_s_barrier();

        const f32x4 xa0 = *(const f32x4*)&xs[cur][a0];
        const f32x4 xa1 = *(const f32x4*)&xs[cur][a1];
        short8 ah, am, al;
        CVT8(xa0, xa1, ah, am, al)

#pragma unroll
        for (int cf = 0; cf < 4; ++cf) {
            const f32x4 wv0 = *(const f32x4*)&wlds[cur][bofs[cf] + b0o];
            const f32x4 wv1 = *(const f32x4*)&wlds[cur][bofs[cf] + b1o];
            short8 bh, bm, bl;
            CVT8(wv0, wv1, bh, bm, bl)
            acc[cf] = MFMA(ah, bh, acc[cf]);
            acc[cf] = MFMA(ah, bm, acc[cf]);
            acc[cf] = MFMA(am, bh, acc[cf]);
            acc[cf] = MFMA(ah, bl, acc[cf]);
            acc[cf] = MFMA(al, bh, acc[cf]);
            acc[cf] = MFMA(am, bm, acc[cf]);
        }
        __builtin_amdgcn_s_barrier();
    }

    // ---- C write: col = lr, row = lk*4 + reg (m89-verified layout)
    const int orow = lk * 4;
#pragma unroll
    for (int j = 0; j < 4; ++j) {
        const int row = rowbase + wid * 16 + orow + j;
        float* dst = part + ((size_t)s * BATCH + row) * NEXP + lr;
#pragma unroll
        for (int cf = 0; cf < 4; ++cf)
            dst[cf * 16] = acc[cf][j];
    }
#undef STAGE
}

// ============================================================================
// Router (r9-proven): sum S partials -> logits; top-2 + softmax weights;
// atomicAdd accumulation; LAST block computes the loss (fused).
// ============================================================================
template<int NS>
__global__ __launch_bounds__(256) void router2(const float* __restrict__ part,
                                               const float* __restrict__ noise,
                                               float* __restrict__ out,
                                               float* __restrict__ probsum,
                                               float* __restrict__ counts,
                                               int* __restrict__ done)
{
    __shared__ float sps[4][64];
    __shared__ float scnt[4][64];
    __shared__ int lastFlag;

    const int t = threadIdx.x;
    const int w = t >> 6;
    const int lane = t & 63;
    const int wg = blockIdx.x * 4 + w;   // 0..1023

    float* out_idx = out;
    float* out_w = out + 16384;
    float* out_logits = out + 32768;

    float psum_local = 0.f;
    float cnt_local = 0.f;

    for (int r = 0; r < 8; ++r) {
        const int row = wg * 8 + r;
        float lgt = 0.f;
#pragma unroll
        for (int s = 0; s < NS; ++s)
            lgt += part[((size_t)s * BATCH + row) * NEXP + lane];
        out_logits[(size_t)row * NEXP + lane] = lgt;

        const float ny = lgt + 0.1f * noise[(size_t)row * NEXP + lane];

        float v1 = ny; int i1 = lane;
#pragma unroll
        for (int m = 32; m >= 1; m >>= 1) {
            float ov = __shfl_xor(v1, m);
            int oi = __shfl_xor(i1, m);
            if (ov > v1 || (ov == v1 && oi < i1)) { v1 = ov; i1 = oi; }
        }
        float v2 = (lane == i1) ? -1e30f : ny; int i2 = lane;
#pragma unroll
        for (int m = 32; m >= 1; m >>= 1) {
            float ov = __shfl_xor(v2, m);
            int oi = __shfl_xor(i2, m);
            if (ov > v2 || (ov == v2 && oi < i2)) { v2 = ov; i2 = oi; }
        }

        if (lane == 0) {
            const float d = expf(v2 - v1);
            const float w1 = 1.0f / (1.0f + d);
            out_idx[row * 2 + 0] = (float)i1;
            out_idx[row * 2 + 1] = (float)i2;
            out_w[row * 2 + 0] = w1;
            out_w[row * 2 + 1] = 1.0f - w1;
        }

        float m = lgt;
#pragma unroll
        for (int ss = 32; ss >= 1; ss >>= 1) m = fmaxf(m, __shfl_xor(m, ss));
        const float p = expf(lgt - m);
        float sum = p;
#pragma unroll
        for (int ss = 32; ss >= 1; ss >>= 1) sum += __shfl_xor(sum, ss);
        psum_local += p / sum;
        cnt_local += (lane == i1 ? 1.f : 0.f) + (lane == i2 ? 1.f : 0.f);
    }

    sps[w][lane] = psum_local;
    scnt[w][lane] = cnt_local;
    __syncthreads();
    if (t < 64) {
        float ssum = 0.f, c = 0.f;
#pragma unroll
        for (int ww = 0; ww < 4; ++ww) { ssum += sps[ww][t]; c += scnt[ww][t]; }
        atomicAdd(&probsum[t], ssum);
        atomicAdd(&counts[t], c);
    }
    __syncthreads();
    if (t == 0) {
        __threadfence();
        lastFlag = (atomicAdd(done, 1) == (int)gridDim.x - 1) ? 1 : 0;
    }
    __syncthreads();
    if (lastFlag && t < 64) {
        const float ps = __hip_atomic_load(&probsum[t], __ATOMIC_RELAXED,
                                           __HIP_MEMORY_SCOPE_AGENT);
        const float ct = __hip_atomic_load(&counts[t], __ATOMIC_RELAXED,
                                           __HIP_MEMORY_SCOPE_AGENT);
        float v = ps * ct;
#pragma unroll
        for (int ss = 32; ss >= 1; ss >>= 1) v += __shfl_xor(v, ss);
        if (t == 0)
            out[557056] = (float)NEXP * v / ((float)BATCH * (float)BATCH);
    }
}

// ============================================================================
// 2-dispatch pipeline: gemm (fp32-W in-kernel convert, + zero), router(+loss).
// ============================================================================
extern "C" void kernel_launch(void* const* d_in, const int* in_sizes, int n_in,
                              void* d_out, int out_size, void* d_ws, size_t ws_size,
                              hipStream_t stream)
{
    const float* x = (const float*)d_in[0];
    const float* W = (const float*)d_in[1];
    const float* noise = (const float*)d_in[2];
    float* out = (float*)d_out;
    float* ws = (float*)d_ws;

    float* probsum = ws;                                   // 64 floats
    float* counts = ws + 64;                               // 64 floats
    int* done = (int*)(ws + 128);                          // 1 int
    float* part = ws + 512;                                // S * 8192 * 64 floats

    int S = 1;
    for (int cand = 8; cand >= 1; cand >>= 1) {
        const size_t need = (512 + (size_t)cand * BATCH * NEXP) * sizeof(float);
        if (ws_size >= need) { S = cand; break; }
    }

    gemm_mfma<<<128 * S, 256, 0, stream>>>(x, W, part, ws, S);
    switch (S) {
        case 8: router2<8><<<256, 256, 0, stream>>>(part, noise, out, probsum, counts, done); break;
        case 4: router2<4><<<256, 256, 0, stream>>>(part, noise, out, probsum, counts, done); break;
        case 2: router2<2><<<256, 256, 0, stream>>>(part, noise, out, probsum, counts, done); break;
        default: router2<1><<<256, 256, 0, stream>>>(part, noise, out, probsum, counts, done); break;
    }
}

// Round 19
// 58.045 us; speedup vs baseline: 1.2573x; 1.2573x over previous
//
#include <hip/hip_runtime.h>
#include <hip/hip_bf16.h>

#define BATCH 8192
#define DMODEL 4096
#define NEXP 64

typedef __attribute__((ext_vector_type(8))) short short8;   // 8 halves (4 VGPR)
typedef __attribute__((ext_vector_type(4))) float f32x4;

#define WF_FLOATS  262144   // 524288 ushorts = 128 ksteps * 4096 (2 fp16 planes)

// direct global->LDS async copy, 16B per lane; LDS dest = wave-uniform base + lane*16
#define GLD16(dst_lds, src_g)                                                  \
    __builtin_amdgcn_global_load_lds(                                          \
        (const __attribute__((address_space(1))) void*)(src_g),                \
        (__attribute__((address_space(3))) void*)(dst_lds), 16, 0, 0)

// ============================================================================
// Build W planes (scaled fp16 2-term split), per-kstep contiguous:
// WF2[ks][plane][cf][lane][j] <- split of W[e=cf*16+(l&15)][k=ks*32+(l>>4)*8+j]
// wh = fp16(w*64); wl = fp16((w*64 - wh)*2048). Block 0 zeroes accumulators.
// ============================================================================
__global__ __launch_bounds__(256) void build_wf(const float* __restrict__ W,
                                                unsigned short* __restrict__ WF2,
                                                float* __restrict__ zbase)
{
    const int t = threadIdx.x;
    if (blockIdx.x == 0) {           // zero ws[0..511]: probsum/counts/done
        zbase[t] = 0.f;
        zbase[t + 256] = 0.f;
    }

    const int gid = blockIdx.x * 256 + t;             // 0..32767
    const int ks = gid >> 8;
    const int cf = (gid >> 6) & 3;
    const int l  = gid & 63;
    const int e  = cf * 16 + (l & 15);
    const int k0 = ks * 32 + (l >> 4) * 8;
    const float* src = W + (size_t)e * DMODEL + k0;

    short8 hv, lv;
#pragma unroll
    for (int j = 0; j < 8; ++j) {
        const float wv = src[j] * 64.0f;              // 2^6 scale (exact)
        const _Float16 h = (_Float16)wv;
        const float r = (wv - (float)h) * 2048.0f;    // 2^11 scale (exact)
        const _Float16 lo = (_Float16)r;
        hv[j] = (short)__builtin_bit_cast(unsigned short, h);
        lv[j] = (short)__builtin_bit_cast(unsigned short, lo);
    }
    const size_t base = (size_t)ks * 4096 + cf * 512 + l * 8;
    *(short8*)&WF2[base]        = hv;
    *(short8*)&WF2[base + 2048] = lv;
}

// ============================================================================
// MFMA GEMM, fp16 3-product split: 256 threads (4 waves), 64x64 tile, BK=32,
// global_load_lds staging (pre-swizzled source), double-buffered LDS 32 KB
// (4 blocks/CU), counted vmcnt(4), 2-barrier phase.
// acc0 = xh*wh (x 2^6); acc1 = xh*wl + xl*wh (x 2^17);
// logits = (acc0 + acc1*2^-11) * 2^-6  -- fp32-accurate (~3e-7).
// Grid = 128 row-groups x S k-splits. part[s][row][e].
// ============================================================================

#define CVTF1(V, J, AH, AL) {                                                 \
    const float xv_ = (V);                                                    \
    const _Float16 h_ = (_Float16)xv_;                                        \
    const float r_ = (xv_ - (float)h_) * 2048.0f;                             \
    const _Float16 l_ = (_Float16)r_;                                         \
    AH[J] = (short)__builtin_bit_cast(unsigned short, h_);                    \
    AL[J] = (short)__builtin_bit_cast(unsigned short, l_); }

#define CVTF8(X0, X1, AH, AL)                                                 \
    CVTF1(X0[0], 0, AH, AL) CVTF1(X0[1], 1, AH, AL)                           \
    CVTF1(X0[2], 2, AH, AL) CVTF1(X0[3], 3, AH, AL)                           \
    CVTF1(X1[0], 4, AH, AL) CVTF1(X1[1], 5, AH, AL)                           \
    CVTF1(X1[2], 6, AH, AL) CVTF1(X1[3], 7, AH, AL)

#define MFMAH(A, B, C) __builtin_amdgcn_mfma_f32_16x16x32_f16(A, B, C, 0, 0, 0)

__global__ __launch_bounds__(256, 4) void gemm_mfma(const float* __restrict__ x,
                                                    const unsigned short* __restrict__ WF2,
                                                    float* __restrict__ part,
                                                    int S)
{
    __shared__ float xs[2][2048];            // A tiles: [buf][64 rows * 32 k], 8 KB each
    __shared__ unsigned short wsh[2][4096];  // B tiles: [buf][2 planes][4 cf][64][8], 8 KB each

    const int t = threadIdx.x;
    const int l = t & 63;
    const int wid = t >> 6;
    const int g = blockIdx.x & 127;          // row group (64 rows)
    const int s = blockIdx.x >> 7;           // k-split
    const int rowbase = g * 64;
    const int kbeg = s * (DMODEL / S);
    const int nsteps = (DMODEL / S) >> 5;    // 32-k steps

    const float* pxa[2];
#pragma unroll
    for (int r = 0; r < 2; ++r) {
        const int tr = wid * 16 + r * 8 + (l >> 3);
        const int ul = (l & 7) ^ (tr & 7);
        pxa[r] = x + (size_t)(rowbase + tr) * DMODEL + kbeg + ul * 4;
    }
    const unsigned short* pwb = WF2 + (size_t)(kbeg >> 5) * 4096 + t * 8;

#define STAGE(BUF, IT) {                                                       \
    _Pragma("unroll")                                                          \
    for (int r_ = 0; r_ < 2; ++r_)                                             \
        GLD16(&xs[BUF][wid * 512 + r_ * 256], pxa[r_] + (size_t)(IT) * 32);    \
    _Pragma("unroll")                                                          \
    for (int r_ = 0; r_ < 2; ++r_)                                             \
        GLD16(&wsh[BUF][r_ * 2048 + wid * 512],                                \
              pwb + (size_t)(IT) * 4096 + r_ * 2048); }

    const int lr = l & 15;
    const int lk = l >> 4;
    const int xr = lr & 7;
    const int trw = wid * 16 + lr;
    const int a0 = trw * 32 + (((lk * 2)     ^ xr) * 4);
    const int a1 = trw * 32 + (((lk * 2 + 1) ^ xr) * 4);

    f32x4 acc0[4] = {};
    f32x4 acc1[4] = {};

    STAGE(0, 0)

    for (int it = 0; it < nsteps; ++it) {
        const int cur = it & 1;
        if (it + 1 < nsteps) {
            STAGE(cur ^ 1, it + 1)
            asm volatile("s_waitcnt vmcnt(4)" ::: "memory");
        } else {
            asm volatile("s_waitcnt vmcnt(0)" ::: "memory");
        }
        __builtin_amdgcn_s_barrier();

        const f32x4 xa0 = *(const f32x4*)&xs[cur][a0];
        const f32x4 xa1 = *(const f32x4*)&xs[cur][a1];
        short8 ah, al;
        CVTF8(xa0, xa1, ah, al)

#pragma unroll
        for (int cf = 0; cf < 4; ++cf) {
            const unsigned short* wp = &wsh[cur][cf * 512 + l * 8];
            const short8 bh = *(const short8*)(wp);
            const short8 bl = *(const short8*)(wp + 2048);
            acc0[cf] = MFMAH(ah, bh, acc0[cf]);
            acc1[cf] = MFMAH(ah, bl, acc1[cf]);
            acc1[cf] = MFMAH(al, bh, acc1[cf]);
        }
        __builtin_amdgcn_s_barrier();
    }

    // ---- C write: col = lr, row = lk*4 + reg (m89-verified layout)
    const int orow = lk * 4;
#pragma unroll
    for (int j = 0; j < 4; ++j) {
        const int row = rowbase + wid * 16 + orow + j;
        float* dst = part + ((size_t)s * BATCH + row) * NEXP + lr;
#pragma unroll
        for (int cf = 0; cf < 4; ++cf)
            dst[cf * 16] = (acc0[cf][j] + acc1[cf][j] * 4.8828125e-4f) * 0.015625f;
    }
#undef STAGE
}

// ============================================================================
// Router (r9-proven): sum S partials -> logits; top-2 + softmax weights;
// atomicAdd accumulation; LAST block computes the loss (fused).
// ============================================================================
template<int NS>
__global__ __launch_bounds__(256) void router2(const float* __restrict__ part,
                                               const float* __restrict__ noise,
                                               float* __restrict__ out,
                                               float* __restrict__ probsum,
                                               float* __restrict__ counts,
                                               int* __restrict__ done)
{
    __shared__ float sps[4][64];
    __shared__ float scnt[4][64];
    __shared__ int lastFlag;

    const int t = threadIdx.x;
    const int w = t >> 6;
    const int lane = t & 63;
    const int wg = blockIdx.x * 4 + w;   // 0..1023

    float* out_idx = out;
    float* out_w = out + 16384;
    float* out_logits = out + 32768;

    float psum_local = 0.f;
    float cnt_local = 0.f;

    for (int r = 0; r < 8; ++r) {
        const int row = wg * 8 + r;
        float lgt = 0.f;
#pragma unroll
        for (int s = 0; s < NS; ++s)
            lgt += part[((size_t)s * BATCH + row) * NEXP + lane];
        out_logits[(size_t)row * NEXP + lane] = lgt;

        const float ny = lgt + 0.1f * noise[(size_t)row * NEXP + lane];

        float v1 = ny; int i1 = lane;
#pragma unroll
        for (int m = 32; m >= 1; m >>= 1) {
            float ov = __shfl_xor(v1, m);
            int oi = __shfl_xor(i1, m);
            if (ov > v1 || (ov == v1 && oi < i1)) { v1 = ov; i1 = oi; }
        }
        float v2 = (lane == i1) ? -1e30f : ny; int i2 = lane;
#pragma unroll
        for (int m = 32; m >= 1; m >>= 1) {
            float ov = __shfl_xor(v2, m);
            int oi = __shfl_xor(i2, m);
            if (ov > v2 || (ov == v2 && oi < i2)) { v2 = ov; i2 = oi; }
        }

        if (lane == 0) {
            const float d = expf(v2 - v1);
            const float w1 = 1.0f / (1.0f + d);
            out_idx[row * 2 + 0] = (float)i1;
            out_idx[row * 2 + 1] = (float)i2;
            out_w[row * 2 + 0] = w1;
            out_w[row * 2 + 1] = 1.0f - w1;
        }

        float m = lgt;
#pragma unroll
        for (int ss = 32; ss >= 1; ss >>= 1) m = fmaxf(m, __shfl_xor(m, ss));
        const float p = expf(lgt - m);
        float sum = p;
#pragma unroll
        for (int ss = 32; ss >= 1; ss >>= 1) sum += __shfl_xor(sum, ss);
        psum_local += p / sum;
        cnt_local += (lane == i1 ? 1.f : 0.f) + (lane == i2 ? 1.f : 0.f);
    }

    sps[w][lane] = psum_local;
    scnt[w][lane] = cnt_local;
    __syncthreads();
    if (t < 64) {
        float ssum = 0.f, c = 0.f;
#pragma unroll
        for (int ww = 0; ww < 4; ++ww) { ssum += sps[ww][t]; c += scnt[ww][t]; }
        atomicAdd(&probsum[t], ssum);
        atomicAdd(&counts[t], c);
    }
    __syncthreads();
    if (t == 0) {
        __threadfence();
        lastFlag = (atomicAdd(done, 1) == (int)gridDim.x - 1) ? 1 : 0;
    }
    __syncthreads();
    if (lastFlag && t < 64) {
        const float ps = __hip_atomic_load(&probsum[t], __ATOMIC_RELAXED,
                                           __HIP_MEMORY_SCOPE_AGENT);
        const float ct = __hip_atomic_load(&counts[t], __ATOMIC_RELAXED,
                                           __HIP_MEMORY_SCOPE_AGENT);
        float v = ps * ct;
#pragma unroll
        for (int ss = 32; ss >= 1; ss >>= 1) v += __shfl_xor(v, ss);
        if (t == 0)
            out[557056] = (float)NEXP * v / ((float)BATCH * (float)BATCH);
    }
}

// ============================================================================
// 3-dispatch pipeline: build_wf(+zero), gemm (fp16 3-product), router(+loss).
// ============================================================================
extern "C" void kernel_launch(void* const* d_in, const int* in_sizes, int n_in,
                              void* d_out, int out_size, void* d_ws, size_t ws_size,
                              hipStream_t stream)
{
    const float* x = (const float*)d_in[0];
    const float* W = (const float*)d_in[1];
    const float* noise = (const float*)d_in[2];
    float* out = (float*)d_out;
    float* ws = (float*)d_ws;

    float* probsum = ws;                                   // 64 floats
    float* counts = ws + 64;                               // 64 floats
    int* done = (int*)(ws + 128);                          // 1 int
    unsigned short* WF2 = (unsigned short*)(ws + 512);     // 1 MB
    float* part = ws + 512 + WF_FLOATS;                    // S * 8192 * 64 floats

    int S = 1;
    const size_t base_floats = 512 + WF_FLOATS;
    for (int cand = 8; cand >= 1; cand >>= 1) {
        const size_t need = (base_floats + (size_t)cand * BATCH * NEXP) * sizeof(float);
        if (ws_size >= need) { S = cand; break; }
    }

    build_wf<<<128, 256, 0, stream>>>(W, WF2, ws);
    gemm_mfma<<<128 * S, 256, 0, stream>>>(x, WF2, part, S);
    switch (S) {
        case 8: router2<8><<<256, 256, 0, stream>>>(part, noise, out, probsum, counts, done); break;
        case 4: router2<4><<<256, 256, 0, stream>>>(part, noise, out, probsum, counts, done); break;
        case 2: router2<2><<<256, 256, 0, stream>>>(part, noise, out, probsum, counts, done); break;
        default: router2<1><<<256, 256, 0, stream>>>(part, noise, out, probsum, counts, done); break;
    }
}